// Round 1
// baseline (451.904 us; speedup 1.0000x reference)
//
#include <hip/hip_runtime.h>
#include <hip/hip_bf16.h>
#include <math.h>

typedef __bf16 bf16x8 __attribute__((ext_vector_type(8)));
typedef float f32x4 __attribute__((ext_vector_type(4)));

__device__ __forceinline__ float b2f(unsigned short h) {
    unsigned int u = ((unsigned int)h) << 16;
    return __builtin_bit_cast(float, u);
}
__device__ __forceinline__ unsigned short f2b(float f) {
    unsigned int u = __builtin_bit_cast(unsigned int, f);
    u += 0x7FFFu + ((u >> 16) & 1u);
    return (unsigned short)(u >> 16);
}

// ---------------- weight convert + transpose:  dst[c*R + r] = bf16(src[r*C + c])
__global__ void k_convT(const float* __restrict__ src, unsigned short* __restrict__ dst,
                        int R, int C) {
    long long i = (long long)blockIdx.x * blockDim.x + threadIdx.x;
    long long total = (long long)R * C;
    if (i >= total) return;
    int c = (int)(i / R);
    int r = (int)(i % R);
    dst[i] = f2b(src[(long long)r * C + c]);
}

// ---------------- LayerNorm: x[16384][768] f32 -> xn bf16
__global__ __launch_bounds__(256) void k_ln(const float* __restrict__ x,
                                            const float* __restrict__ g,
                                            const float* __restrict__ b,
                                            unsigned short* __restrict__ xn) {
    int row = blockIdx.x;
    int t = threadIdx.x;
    const float* xr = x + (long long)row * 768;
    float v0 = xr[t], v1 = xr[t + 256], v2 = xr[t + 512];
    float s = v0 + v1 + v2;
    float q = v0 * v0 + v1 * v1 + v2 * v2;
#pragma unroll
    for (int off = 32; off > 0; off >>= 1) {
        s += __shfl_xor(s, off);
        q += __shfl_xor(q, off);
    }
    __shared__ float ss[4], sq[4];
    int w = t >> 6;
    if ((t & 63) == 0) { ss[w] = s; sq[w] = q; }
    __syncthreads();
    float S_ = ss[0] + ss[1] + ss[2] + ss[3];
    float Q_ = sq[0] + sq[1] + sq[2] + sq[3];
    float mu = S_ * (1.0f / 768.0f);
    float var = Q_ * (1.0f / 768.0f) - mu * mu;
    float rs = rsqrtf(var + 1e-5f);
    unsigned short* xo = xn + (long long)row * 768;
    xo[t]       = f2b((v0 - mu) * rs * g[t]       + b[t]);
    xo[t + 256] = f2b((v1 - mu) * rs * g[t + 256] + b[t + 256]);
    xo[t + 512] = f2b((v2 - mu) * rs * g[t + 512] + b[t + 512]);
}

// ---------------- RoPE + per-head affine: bS[16384][128] -> q,k bf16 [32*512][128]
__global__ __launch_bounds__(128) void k_rope(const unsigned short* __restrict__ bS,
                                              const float* __restrict__ gqk,
                                              const float* __restrict__ bqk,
                                              unsigned short* __restrict__ q,
                                              unsigned short* __restrict__ k) {
    int row = blockIdx.x;     // 0..16383
    int l = row & 511;        // sequence position
    int s = threadIdx.x;      // 0..127
    int j = s & 63;
    int partner = s ^ 64;
    float b0 = b2f(bS[(long long)row * 128 + s]);
    float bp = b2f(bS[(long long)row * 128 + partner]);
    float invf = powf(10000.0f, -(float)j * (1.0f / 64.0f));
    float th = (float)l * invf;
    float sn = sinf(th), cs = cosf(th);
    float sign = (s < 64) ? -1.0f : 1.0f;
    float preq  = b0 * gqk[s]           + bqk[s];
    float preqp = bp * gqk[partner]     + bqk[partner];
    q[(long long)row * 128 + s] = f2b(preq * cs + sign * preqp * sn);
    float prek  = b0 * gqk[128 + s]       + bqk[128 + s];
    float prekp = bp * gqk[128 + partner] + bqk[128 + partner];
    k[(long long)row * 128 + s] = f2b(prek * cs + sign * prekp * sn);
}

// ---------------- unified MFMA GEMM, C = A @ B^T  (A[M][K], B[N][K] both row-major bf16)
// 128x128 tile, BK=64, 4 waves (2x2), each wave 64x64 via 4x4 16x16x32 fragments.
// EPI: 0 = silu+split(u,vT,baseS)+uv_b   1 = qk->relu^2(+w_rel bias)->P
//      2 = PV * u -> gated               3 = + o_b + x -> f32 out
template <int EPI>
__global__ __launch_bounds__(256) void k_gemm(const unsigned short* __restrict__ A,
                                              const unsigned short* __restrict__ B,
                                              int K, long long strideA, long long strideB,
                                              void* p0, void* p1, void* p2, void* p3) {
    __shared__ __align__(16) unsigned short As[128 * 64];
    __shared__ __align__(16) unsigned short Bs[128 * 64];
    int t = threadIdx.x;
    int w = t >> 6, lane = t & 63;
    int wr = w >> 1, wc = w & 1;
    int bx = blockIdx.x, by = blockIdx.y, bz = blockIdx.z;
    const unsigned short* Ab = A + bz * strideA + (long long)by * 128 * K;
    const unsigned short* Bb = B + bz * strideB + (long long)bx * 128 * K;

    f32x4 acc[4][4];
#pragma unroll
    for (int m = 0; m < 4; ++m)
#pragma unroll
        for (int n = 0; n < 4; ++n) acc[m][n] = (f32x4){0.f, 0.f, 0.f, 0.f};

    int rowA = (w << 3) + (lane >> 3);  // row within a 32-row issue group
    int colA = (lane & 7) << 3;         // bf16 col (8-elem granule)

    for (int k0 = 0; k0 < K; k0 += 64) {
#pragma unroll
        for (int i = 0; i < 4; ++i) {
            int r = (i << 5) + rowA;
            __builtin_amdgcn_global_load_lds(
                (const __attribute__((address_space(1))) void*)(Ab + (long long)r * K + k0 + colA),
                (__attribute__((address_space(3))) void*)(&As[(i << 11) + (w << 9)]),
                16, 0, 0);
            __builtin_amdgcn_global_load_lds(
                (const __attribute__((address_space(1))) void*)(Bb + (long long)r * K + k0 + colA),
                (__attribute__((address_space(3))) void*)(&Bs[(i << 11) + (w << 9)]),
                16, 0, 0);
        }
        __syncthreads();
#pragma unroll
        for (int ks = 0; ks < 2; ++ks) {
            bf16x8 af[4], bfr[4];
#pragma unroll
            for (int m = 0; m < 4; ++m)
                af[m] = *(const bf16x8*)&As[((wr << 6) + (m << 4) + (lane & 15)) * 64 +
                                            (ks << 5) + ((lane >> 4) << 3)];
#pragma unroll
            for (int n = 0; n < 4; ++n)
                bfr[n] = *(const bf16x8*)&Bs[((wc << 6) + (n << 4) + (lane & 15)) * 64 +
                                             (ks << 5) + ((lane >> 4) << 3)];
#pragma unroll
            for (int m = 0; m < 4; ++m)
#pragma unroll
                for (int n = 0; n < 4; ++n)
                    acc[m][n] = __builtin_amdgcn_mfma_f32_16x16x32_bf16(af[m], bfr[n],
                                                                        acc[m][n], 0, 0, 0);
        }
        __syncthreads();
    }

    int r0 = (by << 7) + (wr << 6) + ((lane >> 4) << 2);
    int c0 = (bx << 7) + (wc << 6) + (lane & 15);
#pragma unroll
    for (int m = 0; m < 4; ++m) {
#pragma unroll
        for (int n = 0; n < 4; ++n) {
#pragma unroll
            for (int r = 0; r < 4; ++r) {
                int grow = r0 + (m << 4) + r;
                int gcol = c0 + (n << 4);
                float v = acc[m][n][r];
                if constexpr (EPI == 0) {
                    // silu(v + uv_b[gcol]); split u / vT / baseS
                    float c = v + ((const float*)p3)[gcol];
                    float sl = c / (1.0f + expf(-c));
                    unsigned short h = f2b(sl);
                    if (gcol < 1536) {
                        ((unsigned short*)p0)[(long long)grow * 1536 + gcol] = h;
                    } else if (gcol < 3072) {
                        int bb = grow >> 9, mm = grow & 511;
                        ((unsigned short*)p1)[((long long)bb * 1536 + (gcol - 1536)) * 512 + mm] = h;
                    } else {
                        ((unsigned short*)p2)[(long long)grow * 128 + (gcol - 3072)] = h;
                    }
                } else if constexpr (EPI == 1) {
                    float val = v * (1.0f / 512.0f) + ((const float*)p1)[gcol - grow + 511];
                    val = fmaxf(val, 0.0f);
                    val *= val;
                    ((unsigned short*)p0)[((long long)bz * 512 + grow) * 512 + gcol] = f2b(val);
                } else if constexpr (EPI == 2) {
                    long long idx = ((long long)bz * 512 + grow) * 1536 + gcol;
                    float uu = b2f(((const unsigned short*)p1)[idx]);
                    ((unsigned short*)p0)[idx] = f2b(v * uu);
                } else {
                    long long idx = (long long)grow * 768 + gcol;
                    ((float*)p0)[idx] = v + ((const float*)p1)[gcol] + ((const float*)p2)[idx];
                }
            }
        }
    }
}

extern "C" void kernel_launch(void* const* d_in, const int* in_sizes, int n_in,
                              void* d_out, int out_size, void* d_ws, size_t ws_size,
                              hipStream_t stream) {
    const float* x     = (const float*)d_in[0];
    const float* ln_g  = (const float*)d_in[1];
    const float* ln_b  = (const float*)d_in[2];
    const float* uv_W  = (const float*)d_in[3];
    const float* uv_b  = (const float*)d_in[4];
    const float* g_qk  = (const float*)d_in[5];
    const float* b_qk  = (const float*)d_in[6];
    const float* w_rel = (const float*)d_in[7];
    const float* o_W   = (const float*)d_in[8];
    const float* o_b   = (const float*)d_in[9];
    float* out = (float*)d_out;

    char* ws = (char*)d_ws;
    size_t off = 0;
    auto alloc = [&](size_t bytes) {
        void* p = ws + off;
        off += (bytes + 255) & ~(size_t)255;
        return p;
    };
    unsigned short* uvWT = (unsigned short*)alloc(3200ll * 768 * 2);   // [3200][768]
    unsigned short* oWT  = (unsigned short*)alloc(768ll * 1536 * 2);   // [768][1536]
    unsigned short* xn   = (unsigned short*)alloc(16384ll * 768 * 2);  // [16384][768]
    unsigned short* u    = (unsigned short*)alloc(16384ll * 1536 * 2); // [16384][1536]
    unsigned short* vT   = (unsigned short*)alloc(32ll * 1536 * 512 * 2); // [32][1536][512]
    unsigned short* bS   = (unsigned short*)alloc(16384ll * 128 * 2);  // [16384][128]
    unsigned short* q    = (unsigned short*)alloc(32ll * 512 * 128 * 2);
    unsigned short* k    = (unsigned short*)alloc(32ll * 512 * 128 * 2);
    unsigned short* P     = xn; // alias: xn dead after GEMM1; P is [32][512][512]
    unsigned short* gated = u;  // alias: read u[idx] then write gated[idx] in same thread

    // weights -> bf16 transposed
    k_convT<<<(3200 * 768 + 255) / 256, 256, 0, stream>>>(uv_W, uvWT, 768, 3200);
    k_convT<<<(1536 * 768 + 255) / 256, 256, 0, stream>>>(o_W, oWT, 1536, 768);
    // layernorm
    k_ln<<<16384, 256, 0, stream>>>(x, ln_g, ln_b, xn);
    // GEMM1: [16384,3200] = silu(xn @ uvWT^T + uv_b), split u/vT/bS
    k_gemm<0><<<dim3(25, 128, 1), 256, 0, stream>>>(xn, uvWT, 768, 0, 0,
                                                    (void*)u, (void*)vT, (void*)bS, (void*)uv_b);
    // rope
    k_rope<<<16384, 128, 0, stream>>>(bS, g_qk, b_qk, q, k);
    // QK^T per batch -> P (relu^2 kernel)
    k_gemm<1><<<dim3(4, 4, 32), 256, 0, stream>>>(q, k, 128, 512ll * 128, 512ll * 128,
                                                  (void*)P, (void*)w_rel, nullptr, nullptr);
    // PV per batch, gated by u
    k_gemm<2><<<dim3(12, 4, 32), 256, 0, stream>>>(P, vT, 512, 512ll * 512, 1536ll * 512,
                                                   (void*)gated, (void*)u, nullptr, nullptr);
    // out = gated @ oWT^T + o_b + x
    k_gemm<3><<<dim3(6, 128, 1), 256, 0, stream>>>(gated, oWT, 1536, 0, 0,
                                                   (void*)out, (void*)o_b, (void*)x, nullptr);
}

// Round 2
// 358.100 us; speedup vs baseline: 1.2619x; 1.2619x over previous
//
#include <hip/hip_runtime.h>
#include <hip/hip_bf16.h>
#include <math.h>

typedef __bf16 bf16x8 __attribute__((ext_vector_type(8)));
typedef float f32x4 __attribute__((ext_vector_type(4)));
typedef unsigned short u16x4 __attribute__((ext_vector_type(4)));

__device__ __forceinline__ float b2f(unsigned short h) {
    unsigned int u = ((unsigned int)h) << 16;
    return __builtin_bit_cast(float, u);
}
__device__ __forceinline__ unsigned short f2b(float f) {
    unsigned int u = __builtin_bit_cast(unsigned int, f);
    u += 0x7FFFu + ((u >> 16) & 1u);
    return (unsigned short)(u >> 16);
}
__device__ __forceinline__ float silu(float c) {
    return c * __builtin_amdgcn_rcpf(1.0f + __expf(-c));
}

// ---------------- tiled transpose + bf16 convert: dst[C][R] <- src[R][C]
__global__ __launch_bounds__(256) void k_convT(const float* __restrict__ src,
                                               unsigned short* __restrict__ dst,
                                               int R, int C) {
    __shared__ float tile[32][33];
    int tx = threadIdx.x, ty = threadIdx.y;
    int r0 = blockIdx.y << 5, c0 = blockIdx.x << 5;
#pragma unroll
    for (int i = 0; i < 4; ++i)
        tile[ty + 8 * i][tx] = src[(long long)(r0 + ty + 8 * i) * C + c0 + tx];
    __syncthreads();
#pragma unroll
    for (int i = 0; i < 4; ++i)
        dst[(long long)(c0 + ty + 8 * i) * R + r0 + tx] = f2b(tile[tx][ty + 8 * i]);
}

// ---------------- LayerNorm: x[16384][768] f32 -> xn bf16
__global__ __launch_bounds__(256) void k_ln(const float* __restrict__ x,
                                            const float* __restrict__ g,
                                            const float* __restrict__ b,
                                            unsigned short* __restrict__ xn) {
    int row = blockIdx.x;
    int t = threadIdx.x;
    const float* xr = x + (long long)row * 768;
    float v0 = xr[t], v1 = xr[t + 256], v2 = xr[t + 512];
    float s = v0 + v1 + v2;
    float q = v0 * v0 + v1 * v1 + v2 * v2;
#pragma unroll
    for (int off = 32; off > 0; off >>= 1) {
        s += __shfl_xor(s, off);
        q += __shfl_xor(q, off);
    }
    __shared__ float ss[4], sq[4];
    int w = t >> 6;
    if ((t & 63) == 0) { ss[w] = s; sq[w] = q; }
    __syncthreads();
    float S_ = ss[0] + ss[1] + ss[2] + ss[3];
    float Q_ = sq[0] + sq[1] + sq[2] + sq[3];
    float mu = S_ * (1.0f / 768.0f);
    float var = Q_ * (1.0f / 768.0f) - mu * mu;
    float rs = rsqrtf(var + 1e-5f);
    unsigned short* xo = xn + (long long)row * 768;
    xo[t]       = f2b((v0 - mu) * rs * g[t]       + b[t]);
    xo[t + 256] = f2b((v1 - mu) * rs * g[t + 256] + b[t + 256]);
    xo[t + 512] = f2b((v2 - mu) * rs * g[t + 512] + b[t + 512]);
}

// ---------------- RoPE + per-head affine
__global__ __launch_bounds__(128) void k_rope(const unsigned short* __restrict__ bS,
                                              const float* __restrict__ gqk,
                                              const float* __restrict__ bqk,
                                              unsigned short* __restrict__ q,
                                              unsigned short* __restrict__ k) {
    int row = blockIdx.x;     // 0..16383
    int l = row & 511;
    int s = threadIdx.x;      // 0..127
    int j = s & 63;
    int partner = s ^ 64;
    float b0 = b2f(bS[(long long)row * 128 + s]);
    float bp = b2f(bS[(long long)row * 128 + partner]);
    float invf = __expf((float)j * -0.14391156831f);  // 10000^(-j/64)
    float th = (float)l * invf;
    float sn, cs;
    __sincosf(th, &sn, &cs);
    float sign = (s < 64) ? -1.0f : 1.0f;
    float preq  = b0 * gqk[s]           + bqk[s];
    float preqp = bp * gqk[partner]     + bqk[partner];
    q[(long long)row * 128 + s] = f2b(preq * cs + sign * preqp * sn);
    float prek  = b0 * gqk[128 + s]       + bqk[128 + s];
    float prekp = bp * gqk[128 + partner] + bqk[128 + partner];
    k[(long long)row * 128 + s] = f2b(prek * cs + sign * prekp * sn);
}

// ---------------- unified MFMA GEMM, C = A @ B^T  (A[M][K], B[N][K] row-major bf16)
// 128x128 tile, BK=64, 4 waves (2x2), 4x4 16x16x32 fragments per wave.
// SWAP=true: compute C^T fragments (mfma(b,a)) -> thread holds 4 consecutive
//            OUTPUT COLS at one row -> packed 8B row-major stores.
// EPI: 0=u(silu)  4=vT(silu, transposed store, SWAP=false)  5=bS(silu)
//      1=P(relu^2+bias)  2=gated(PV*u)  3=out f32 (+o_b+x)
template <int EPI, bool SWAP, bool SWZ>
__global__ __launch_bounds__(256) void k_gemm(const unsigned short* __restrict__ A,
                                              const unsigned short* __restrict__ B,
                                              int K, long long strideA, long long strideB,
                                              void* p0, const void* p1, const void* p2,
                                              const void* p3) {
    __shared__ __align__(16) unsigned short As[128 * 64];
    __shared__ __align__(16) unsigned short Bs[128 * 64];
    int t = threadIdx.x;
    int w = t >> 6, lane = t & 63;
    int wr = w >> 1, wc = w & 1;
    int bx = blockIdx.x, by = blockIdx.y, bz = blockIdx.z;
    if constexpr (SWZ) {  // XCD-chunked bijective swizzle (grid.x*grid.y % 8 == 0)
        int gx = gridDim.x;
        int nb = gx * gridDim.y;
        int bid = by * gx + bx;
        int s = (bid & 7) * (nb >> 3) + (bid >> 3);
        bx = s % gx;
        by = s / gx;
    }
    const unsigned short* Ab = A + bz * strideA + (long long)by * 128 * K;
    const unsigned short* Bb = B + bz * strideB + (long long)bx * 128 * K;

    f32x4 acc[4][4];
#pragma unroll
    for (int m = 0; m < 4; ++m)
#pragma unroll
        for (int n = 0; n < 4; ++n) acc[m][n] = (f32x4){0.f, 0.f, 0.f, 0.f};

    int rowA = (w << 3) + (lane >> 3);
    int colA = (lane & 7) << 3;

    for (int k0 = 0; k0 < K; k0 += 64) {
#pragma unroll
        for (int i = 0; i < 4; ++i) {
            int r = (i << 5) + rowA;
            __builtin_amdgcn_global_load_lds(
                (const __attribute__((address_space(1))) void*)(Ab + (long long)r * K + k0 + colA),
                (__attribute__((address_space(3))) void*)(&As[(i << 11) + (w << 9)]),
                16, 0, 0);
            __builtin_amdgcn_global_load_lds(
                (const __attribute__((address_space(1))) void*)(Bb + (long long)r * K + k0 + colA),
                (__attribute__((address_space(3))) void*)(&Bs[(i << 11) + (w << 9)]),
                16, 0, 0);
        }
        __syncthreads();
#pragma unroll
        for (int ks = 0; ks < 2; ++ks) {
            bf16x8 af[4], bfr[4];
#pragma unroll
            for (int m = 0; m < 4; ++m)
                af[m] = *(const bf16x8*)&As[((wr << 6) + (m << 4) + (lane & 15)) * 64 +
                                            (ks << 5) + ((lane >> 4) << 3)];
#pragma unroll
            for (int n = 0; n < 4; ++n)
                bfr[n] = *(const bf16x8*)&Bs[((wc << 6) + (n << 4) + (lane & 15)) * 64 +
                                             (ks << 5) + ((lane >> 4) << 3)];
#pragma unroll
            for (int m = 0; m < 4; ++m)
#pragma unroll
                for (int n = 0; n < 4; ++n) {
                    if constexpr (SWAP)
                        acc[m][n] = __builtin_amdgcn_mfma_f32_16x16x32_bf16(bfr[n], af[m],
                                                                            acc[m][n], 0, 0, 0);
                    else
                        acc[m][n] = __builtin_amdgcn_mfma_f32_16x16x32_bf16(af[m], bfr[n],
                                                                            acc[m][n], 0, 0, 0);
                }
        }
        __syncthreads();
    }

    int c15 = lane & 15, qq = lane >> 4;
    if constexpr (SWAP) {
        // thread holds: out_row = rowb + m*16, cols colb + n*16 + {0..3}
        int rowb = (by << 7) + (wr << 6) + c15;
        int colb = (bx << 7) + (wc << 6) + (qq << 2);
#pragma unroll
        for (int m = 0; m < 4; ++m) {
#pragma unroll
            for (int n = 0; n < 4; ++n) {
                int grow = rowb + (m << 4);
                int gcol = colb + (n << 4);
                f32x4 a = acc[m][n];
                if constexpr (EPI == 0 || EPI == 5) {
                    constexpr int OSTR = (EPI == 0) ? 1536 : 128;
                    f32x4 bb = *(const f32x4*)((const float*)p3 + gcol);
                    u16x4 o;
#pragma unroll
                    for (int i = 0; i < 4; ++i) o[i] = f2b(silu(a[i] + bb[i]));
                    *(u16x4*)((unsigned short*)p0 + (long long)grow * OSTR + gcol) = o;
                } else if constexpr (EPI == 1) {
                    const float* wrel = (const float*)p1;
                    int base = gcol - grow + 511;
                    u16x4 o;
#pragma unroll
                    for (int i = 0; i < 4; ++i) {
                        float val = a[i] * (1.0f / 512.0f) + wrel[base + i];
                        val = fmaxf(val, 0.0f);
                        o[i] = f2b(val * val);
                    }
                    *(u16x4*)((unsigned short*)p0 +
                              ((long long)(bz * 512 + grow)) * 512 + gcol) = o;
                } else if constexpr (EPI == 2) {
                    long long idx = ((long long)(bz * 512 + grow)) * 1536 + gcol;
                    u16x4 uu = *(const u16x4*)((const unsigned short*)p1 + idx);
                    u16x4 o;
#pragma unroll
                    for (int i = 0; i < 4; ++i) o[i] = f2b(a[i] * b2f(uu[i]));
                    *(u16x4*)((unsigned short*)p0 + idx) = o;
                } else {  // EPI == 3: f32 out = acc + o_b + x
                    long long idx = (long long)grow * 768 + gcol;
                    f32x4 xv = *(const f32x4*)((const float*)p2 + idx);
                    f32x4 ob = *(const f32x4*)((const float*)p1 + gcol);
                    f32x4 o;
#pragma unroll
                    for (int i = 0; i < 4; ++i) o[i] = a[i] + ob[i] + xv[i];
                    *(f32x4*)((float*)p0 + idx) = o;
                }
            }
        }
    } else {
        // EPI == 4 (vT): thread holds out rows rowb+m*16+{0..3} (contig in vT), col e
        int rowb = (by << 7) + (wr << 6) + (qq << 2);
        int col = (bx << 7) + (wc << 6) + c15;
#pragma unroll
        for (int m = 0; m < 4; ++m) {
#pragma unroll
            for (int n = 0; n < 4; ++n) {
                int grow = rowb + (m << 4);       // 4 contiguous m (same batch)
                int e = col + (n << 4);
                float bias = ((const float*)p3)[1536 + e];
                f32x4 a = acc[m][n];
                u16x4 o;
#pragma unroll
                for (int i = 0; i < 4; ++i) o[i] = f2b(silu(a[i] + bias));
                int bb = grow >> 9, mm = grow & 511;
                *(u16x4*)((unsigned short*)p0 + ((long long)bb * 1536 + e) * 512 + mm) = o;
            }
        }
    }
}

extern "C" void kernel_launch(void* const* d_in, const int* in_sizes, int n_in,
                              void* d_out, int out_size, void* d_ws, size_t ws_size,
                              hipStream_t stream) {
    const float* x     = (const float*)d_in[0];
    const float* ln_g  = (const float*)d_in[1];
    const float* ln_b  = (const float*)d_in[2];
    const float* uv_W  = (const float*)d_in[3];
    const float* uv_b  = (const float*)d_in[4];
    const float* g_qk  = (const float*)d_in[5];
    const float* b_qk  = (const float*)d_in[6];
    const float* w_rel = (const float*)d_in[7];
    const float* o_W   = (const float*)d_in[8];
    const float* o_b   = (const float*)d_in[9];
    float* out = (float*)d_out;

    char* ws = (char*)d_ws;
    size_t off = 0;
    auto alloc = [&](size_t bytes) {
        void* p = ws + off;
        off += (bytes + 255) & ~(size_t)255;
        return p;
    };
    unsigned short* uvWT = (unsigned short*)alloc(3200ll * 768 * 2);   // [3200][768]
    unsigned short* oWT  = (unsigned short*)alloc(768ll * 1536 * 2);   // [768][1536]
    unsigned short* xn   = (unsigned short*)alloc(16384ll * 768 * 2);  // [16384][768]
    unsigned short* u    = (unsigned short*)alloc(16384ll * 1536 * 2); // [16384][1536]
    unsigned short* vT   = (unsigned short*)alloc(32ll * 1536 * 512 * 2); // [32][1536][512]
    unsigned short* bS   = (unsigned short*)alloc(16384ll * 128 * 2);  // [16384][128]
    unsigned short* q    = (unsigned short*)alloc(32ll * 512 * 128 * 2);
    unsigned short* k    = (unsigned short*)alloc(32ll * 512 * 128 * 2);
    unsigned short* P     = xn; // alias: xn dead after GEMM1 trio
    unsigned short* gated = u;  // alias: same-thread read-then-write

    // weights -> bf16 transposed (coalesced tiled transpose)
    k_convT<<<dim3(100, 24), dim3(32, 8), 0, stream>>>(uv_W, uvWT, 768, 3200);
    k_convT<<<dim3(24, 48), dim3(32, 8), 0, stream>>>(o_W, oWT, 1536, 768);
    // layernorm
    k_ln<<<16384, 256, 0, stream>>>(x, ln_g, ln_b, xn);
    // GEMM1 split: u | vT | bS  (silu + uv_b fused)
    k_gemm<0, true, true><<<dim3(12, 128), 256, 0, stream>>>(
        xn, uvWT, 768, 0, 0, (void*)u, nullptr, nullptr, (const void*)uv_b);
    k_gemm<4, false, true><<<dim3(12, 128), 256, 0, stream>>>(
        xn, uvWT + 1536ll * 768, 768, 0, 0, (void*)vT, nullptr, nullptr, (const void*)uv_b);
    k_gemm<5, true, true><<<dim3(1, 128), 256, 0, stream>>>(
        xn, uvWT + 3072ll * 768, 768, 0, 0, (void*)bS, nullptr, nullptr,
        (const void*)(uv_b + 3072));
    // rope
    k_rope<<<16384, 128, 0, stream>>>(bS, g_qk, b_qk, q, k);
    // QK^T per batch -> P (relu^2 kernel)
    k_gemm<1, true, false><<<dim3(4, 4, 32), 256, 0, stream>>>(
        q, k, 128, 512ll * 128, 512ll * 128, (void*)P, (const void*)w_rel, nullptr, nullptr);
    // PV per batch, gated by u
    k_gemm<2, true, false><<<dim3(12, 4, 32), 256, 0, stream>>>(
        P, vT, 512, 512ll * 512, 1536ll * 512, (void*)gated, (const void*)u, nullptr, nullptr);
    // out = gated @ oWT^T + o_b + x
    k_gemm<3, true, true><<<dim3(6, 128), 256, 0, stream>>>(
        gated, oWT, 1536, 0, 0, (void*)out, (const void*)o_b, (const void*)x, nullptr);
}

// Round 3
// 313.659 us; speedup vs baseline: 1.4407x; 1.1417x over previous
//
#include <hip/hip_runtime.h>
#include <hip/hip_bf16.h>
#include <math.h>

typedef __bf16 bf16x8 __attribute__((ext_vector_type(8)));
typedef float f32x4 __attribute__((ext_vector_type(4)));
typedef unsigned short u16x4 __attribute__((ext_vector_type(4)));

__device__ __forceinline__ float b2f(unsigned short h) {
    unsigned int u = ((unsigned int)h) << 16;
    return __builtin_bit_cast(float, u);
}
__device__ __forceinline__ unsigned short f2b(float f) {
    unsigned int u = __builtin_bit_cast(unsigned int, f);
    u += 0x7FFFu + ((u >> 16) & 1u);
    return (unsigned short)(u >> 16);
}
__device__ __forceinline__ float silu(float c) {
    return c * __builtin_amdgcn_rcpf(1.0f + __expf(-c));
}

// ---------------- tiled transpose + bf16 convert: dst[C][R] <- src[R][C]
__global__ __launch_bounds__(256) void k_convT(const float* __restrict__ src,
                                               unsigned short* __restrict__ dst,
                                               int R, int C) {
    __shared__ float tile[32][33];
    int tx = threadIdx.x, ty = threadIdx.y;
    int r0 = blockIdx.y << 5, c0 = blockIdx.x << 5;
#pragma unroll
    for (int i = 0; i < 4; ++i)
        tile[ty + 8 * i][tx] = src[(long long)(r0 + ty + 8 * i) * C + c0 + tx];
    __syncthreads();
#pragma unroll
    for (int i = 0; i < 4; ++i)
        dst[(long long)(c0 + ty + 8 * i) * R + r0 + tx] = f2b(tile[tx][ty + 8 * i]);
}

// ---------------- LayerNorm: x[16384][768] f32 -> xn bf16
__global__ __launch_bounds__(256) void k_ln(const float* __restrict__ x,
                                            const float* __restrict__ g,
                                            const float* __restrict__ b,
                                            unsigned short* __restrict__ xn) {
    int row = blockIdx.x;
    int t = threadIdx.x;
    const float* xr = x + (long long)row * 768;
    float v0 = xr[t], v1 = xr[t + 256], v2 = xr[t + 512];
    float s = v0 + v1 + v2;
    float q = v0 * v0 + v1 * v1 + v2 * v2;
#pragma unroll
    for (int off = 32; off > 0; off >>= 1) {
        s += __shfl_xor(s, off);
        q += __shfl_xor(q, off);
    }
    __shared__ float ss[4], sq[4];
    int w = t >> 6;
    if ((t & 63) == 0) { ss[w] = s; sq[w] = q; }
    __syncthreads();
    float S_ = ss[0] + ss[1] + ss[2] + ss[3];
    float Q_ = sq[0] + sq[1] + sq[2] + sq[3];
    float mu = S_ * (1.0f / 768.0f);
    float var = Q_ * (1.0f / 768.0f) - mu * mu;
    float rs = rsqrtf(var + 1e-5f);
    unsigned short* xo = xn + (long long)row * 768;
    xo[t]       = f2b((v0 - mu) * rs * g[t]       + b[t]);
    xo[t + 256] = f2b((v1 - mu) * rs * g[t + 256] + b[t + 256]);
    xo[t + 512] = f2b((v2 - mu) * rs * g[t + 512] + b[t + 512]);
}

// ---------------- RoPE + per-head affine
__global__ __launch_bounds__(128) void k_rope(const unsigned short* __restrict__ bS,
                                              const float* __restrict__ gqk,
                                              const float* __restrict__ bqk,
                                              unsigned short* __restrict__ q,
                                              unsigned short* __restrict__ k) {
    int row = blockIdx.x;
    int l = row & 511;
    int s = threadIdx.x;
    int j = s & 63;
    int partner = s ^ 64;
    float b0 = b2f(bS[(long long)row * 128 + s]);
    float bp = b2f(bS[(long long)row * 128 + partner]);
    float invf = __expf((float)j * -0.14391156831f);
    float th = (float)l * invf;
    float sn, cs;
    __sincosf(th, &sn, &cs);
    float sign = (s < 64) ? -1.0f : 1.0f;
    float preq  = b0 * gqk[s]           + bqk[s];
    float preqp = bp * gqk[partner]     + bqk[partner];
    q[(long long)row * 128 + s] = f2b(preq * cs + sign * preqp * sn);
    float prek  = b0 * gqk[128 + s]       + bqk[128 + s];
    float prekp = bp * gqk[128 + partner] + bqk[128 + partner];
    k[(long long)row * 128 + s] = f2b(prek * cs + sign * prekp * sn);
}

// ================= 128^2 2-phase kernel (kept for QK (EPI=1) and bS (EPI=5))
template <int EPI, bool SWAP, bool SWZ>
__global__ __launch_bounds__(256) void k_gemm(const unsigned short* __restrict__ A,
                                              const unsigned short* __restrict__ B,
                                              int K, long long strideA, long long strideB,
                                              void* p0, const void* p1, const void* p2,
                                              const void* p3) {
    __shared__ __align__(16) unsigned short As[128 * 64];
    __shared__ __align__(16) unsigned short Bs[128 * 64];
    int t = threadIdx.x;
    int w = t >> 6, lane = t & 63;
    int wr = w >> 1, wc = w & 1;
    int bx = blockIdx.x, by = blockIdx.y, bz = blockIdx.z;
    if constexpr (SWZ) {
        int gx = gridDim.x;
        int nb = gx * gridDim.y;
        int bid = by * gx + bx;
        int s = (bid & 7) * (nb >> 3) + (bid >> 3);
        bx = s % gx;
        by = s / gx;
    }
    const unsigned short* Ab = A + bz * strideA + (long long)by * 128 * K;
    const unsigned short* Bb = B + bz * strideB + (long long)bx * 128 * K;

    f32x4 acc[4][4];
#pragma unroll
    for (int m = 0; m < 4; ++m)
#pragma unroll
        for (int n = 0; n < 4; ++n) acc[m][n] = (f32x4){0.f, 0.f, 0.f, 0.f};

    int rowA = (w << 3) + (lane >> 3);
    int colA = (lane & 7) << 3;

    for (int k0 = 0; k0 < K; k0 += 64) {
#pragma unroll
        for (int i = 0; i < 4; ++i) {
            int r = (i << 5) + rowA;
            __builtin_amdgcn_global_load_lds(
                (const __attribute__((address_space(1))) void*)(Ab + (long long)r * K + k0 + colA),
                (__attribute__((address_space(3))) void*)(&As[(i << 11) + (w << 9)]),
                16, 0, 0);
            __builtin_amdgcn_global_load_lds(
                (const __attribute__((address_space(1))) void*)(Bb + (long long)r * K + k0 + colA),
                (__attribute__((address_space(3))) void*)(&Bs[(i << 11) + (w << 9)]),
                16, 0, 0);
        }
        __syncthreads();
#pragma unroll
        for (int ks = 0; ks < 2; ++ks) {
            bf16x8 af[4], bfr[4];
#pragma unroll
            for (int m = 0; m < 4; ++m)
                af[m] = *(const bf16x8*)&As[((wr << 6) + (m << 4) + (lane & 15)) * 64 +
                                            (ks << 5) + ((lane >> 4) << 3)];
#pragma unroll
            for (int n = 0; n < 4; ++n)
                bfr[n] = *(const bf16x8*)&Bs[((wc << 6) + (n << 4) + (lane & 15)) * 64 +
                                             (ks << 5) + ((lane >> 4) << 3)];
#pragma unroll
            for (int m = 0; m < 4; ++m)
#pragma unroll
                for (int n = 0; n < 4; ++n) {
                    if constexpr (SWAP)
                        acc[m][n] = __builtin_amdgcn_mfma_f32_16x16x32_bf16(bfr[n], af[m],
                                                                            acc[m][n], 0, 0, 0);
                    else
                        acc[m][n] = __builtin_amdgcn_mfma_f32_16x16x32_bf16(af[m], bfr[n],
                                                                            acc[m][n], 0, 0, 0);
                }
        }
        __syncthreads();
    }

    int c15 = lane & 15, qq = lane >> 4;
    // SWAP layout: row = rowb + m*16, cols colb + n*16 + {0..3}
    int rowb = (by << 7) + (wr << 6) + c15;
    int colb = (bx << 7) + (wc << 6) + (qq << 2);
#pragma unroll
    for (int m = 0; m < 4; ++m) {
#pragma unroll
        for (int n = 0; n < 4; ++n) {
            int grow = rowb + (m << 4);
            int gcol = colb + (n << 4);
            f32x4 a = acc[m][n];
            if constexpr (EPI == 5) {
                f32x4 bb = *(const f32x4*)((const float*)p3 + gcol);
                u16x4 o;
#pragma unroll
                for (int i = 0; i < 4; ++i) o[i] = f2b(silu(a[i] + bb[i]));
                *(u16x4*)((unsigned short*)p0 + (long long)grow * 128 + gcol) = o;
            } else {  // EPI == 1 : P = relu^2(qk/L + bias)
                const float* wrel = (const float*)p1;
                int base = gcol - grow + 511;
                u16x4 o;
#pragma unroll
                for (int i = 0; i < 4; ++i) {
                    float val = a[i] * (1.0f / 512.0f) + wrel[base + i];
                    val = fmaxf(val, 0.0f);
                    o[i] = f2b(val * val);
                }
                *(u16x4*)((unsigned short*)p0 +
                          ((long long)(bz * 512 + grow)) * 512 + gcol) = o;
            }
        }
    }
}

// ================= 256^2 8-phase kernel (T1+T2+T3+T4+T5)
#define AS1P const __attribute__((address_space(1))) void*
#define AS3P __attribute__((address_space(3))) void*

// stage 64 rows x 64k (8KB) of a [256][64] bf16 LDS tile; linear dest, swizzled src
__device__ __forceinline__ void stage64(const unsigned short* __restrict__ g, long long ldk,
                                        unsigned short* lds, int r0, int w, int lane) {
    int row = r0 + (w << 3) + (lane >> 3);
    int colb = (lane & 7) << 4;
    int scolb = colb ^ ((row & 7) << 4);
    __builtin_amdgcn_global_load_lds(
        (AS1P)((const char*)g + (long long)row * (ldk * 2) + scolb),
        (AS3P)((char*)lds + (r0 << 7) + (w << 10)), 16, 0, 0);
}
__device__ __forceinline__ const bf16x8* frag_ptr(const unsigned short* tile, int row, int colb) {
    return (const bf16x8*)((const char*)tile + (row << 7) + (colb ^ ((row & 7) << 4)));
}

// EPI: 0=u(silu+uv_b)  4=vT(silu, transposed, SWAP=false)  2=gated(PV*u)  3=out f32(+o_b+x)
template <int EPI, bool SWAP, bool SWZ>
__global__ __launch_bounds__(512, 2) void k_gemm8(const unsigned short* __restrict__ A,
                                                  const unsigned short* __restrict__ B,
                                                  int K, long long strideA, long long strideB,
                                                  void* p0, const void* p1, const void* p2,
                                                  const void* p3) {
    __shared__ __align__(16) unsigned short As[2][256 * 64];
    __shared__ __align__(16) unsigned short Bs[2][256 * 64];
    int t = threadIdx.x;
    int w = t >> 6, lane = t & 63;
    int wr = w >> 2, wc = w & 3;
    int c15 = lane & 15, qq = lane >> 4;
    int bx = blockIdx.x, by = blockIdx.y, bz = blockIdx.z;
    if constexpr (SWZ) {
        int gx = gridDim.x;
        int nb = gx * gridDim.y;
        int bid = by * gx + bx;
        int s = (bid & 7) * (nb >> 3) + (bid >> 3);
        bx = s % gx;
        by = s / gx;
    }
    const unsigned short* Ab = A + bz * strideA + (long long)by * 256 * K;
    const unsigned short* Bb = B + bz * strideB + (long long)bx * 256 * K;

    f32x4 acc[8][4];
#pragma unroll
    for (int m = 0; m < 8; ++m)
#pragma unroll
        for (int n = 0; n < 4; ++n) acc[m][n] = (f32x4){0.f, 0.f, 0.f, 0.f};

    // prologue: stage tile 0 into buf 0
#pragma unroll
    for (int h = 0; h < 4; ++h) {
        stage64(Ab, K, &As[0][0], h << 6, w, lane);
        stage64(Bb, K, &Bs[0][0], h << 6, w, lane);
    }
    asm volatile("s_waitcnt vmcnt(0)" ::: "memory");
    __builtin_amdgcn_s_barrier();

    const int NT = K >> 6;
    for (int kt = 0; kt < NT; ++kt) {
        const int cur = kt & 1;
        const unsigned short* At = &As[cur][0];
        const unsigned short* Bt = &Bs[cur][0];
        unsigned short* Asn = &As[cur ^ 1][0];
        unsigned short* Bsn = &Bs[cur ^ 1][0];
        const unsigned short* An = Ab + (long long)(kt + 1) * 64;
        const unsigned short* Bn = Bb + (long long)(kt + 1) * 64;
        const bool pf = (kt + 1 < NT);
        bf16x8 bfr[4][2], af[2][2];

#define LOAD_A(p)                                                                   \
    _Pragma("unroll") for (int j = 0; j < 2; ++j)                                   \
        _Pragma("unroll") for (int ks = 0; ks < 2; ++ks)                            \
            af[j][ks] = *frag_ptr(At, wr * 128 + (2 * (p) + j) * 16 + c15,          \
                                  ks * 64 + qq * 16);
#define DO_MFMA(p)                                                                  \
    __builtin_amdgcn_s_setprio(1);                                                  \
    _Pragma("unroll") for (int j = 0; j < 2; ++j)                                   \
        _Pragma("unroll") for (int n = 0; n < 4; ++n)                               \
            _Pragma("unroll") for (int ks = 0; ks < 2; ++ks) {                      \
                if constexpr (SWAP)                                                 \
                    acc[2 * (p) + j][n] = __builtin_amdgcn_mfma_f32_16x16x32_bf16(  \
                        bfr[n][ks], af[j][ks], acc[2 * (p) + j][n], 0, 0, 0);       \
                else                                                                \
                    acc[2 * (p) + j][n] = __builtin_amdgcn_mfma_f32_16x16x32_bf16(  \
                        af[j][ks], bfr[n][ks], acc[2 * (p) + j][n], 0, 0, 0);       \
            }                                                                       \
    __builtin_amdgcn_s_setprio(0);

        // ---- phase 0: B frags + A m0,m1; stage next A (4 issues)
#pragma unroll
        for (int n = 0; n < 4; ++n)
#pragma unroll
            for (int ks = 0; ks < 2; ++ks)
                bfr[n][ks] = *frag_ptr(Bt, wc * 64 + n * 16 + c15, ks * 64 + qq * 16);
        LOAD_A(0)
        if (pf) {
            stage64(An, K, Asn, 0, w, lane);
            stage64(An, K, Asn, 64, w, lane);
            stage64(An, K, Asn, 128, w, lane);
            stage64(An, K, Asn, 192, w, lane);
        }
        __builtin_amdgcn_s_barrier();
        asm volatile("s_waitcnt lgkmcnt(0)" ::: "memory");
        DO_MFMA(0)
        __builtin_amdgcn_s_barrier();
        // ---- phase 1: A m2,m3; stage next B half 0
        LOAD_A(1)
        if (pf) {
            stage64(Bn, K, Bsn, 0, w, lane);
            stage64(Bn, K, Bsn, 64, w, lane);
        }
        __builtin_amdgcn_s_barrier();
        asm volatile("s_waitcnt lgkmcnt(0)" ::: "memory");
        DO_MFMA(1)
        __builtin_amdgcn_s_barrier();
        // ---- phase 2: A m4,m5; stage next B half 1
        LOAD_A(2)
        if (pf) {
            stage64(Bn, K, Bsn, 128, w, lane);
            stage64(Bn, K, Bsn, 192, w, lane);
        }
        __builtin_amdgcn_s_barrier();
        asm volatile("s_waitcnt lgkmcnt(0)" ::: "memory");
        DO_MFMA(2)
        __builtin_amdgcn_s_barrier();
        // ---- phase 3: A m6,m7; iter-boundary wait
        LOAD_A(3)
        __builtin_amdgcn_s_barrier();
        asm volatile("s_waitcnt lgkmcnt(0)" ::: "memory");
        DO_MFMA(3)
        asm volatile("s_waitcnt vmcnt(0)" ::: "memory");
        __builtin_amdgcn_s_barrier();
#undef LOAD_A
#undef DO_MFMA
    }

    if constexpr (SWAP) {
        int rowb = by * 256 + wr * 128 + c15;
        int colb = bx * 256 + wc * 64 + (qq << 2);
#pragma unroll
        for (int m = 0; m < 8; ++m) {
#pragma unroll
            for (int n = 0; n < 4; ++n) {
                int R = rowb + m * 16;
                int C = colb + n * 16;
                f32x4 a = acc[m][n];
                if constexpr (EPI == 0) {
                    f32x4 bb = *(const f32x4*)((const float*)p3 + C);
                    u16x4 o;
#pragma unroll
                    for (int i = 0; i < 4; ++i) o[i] = f2b(silu(a[i] + bb[i]));
                    *(u16x4*)((unsigned short*)p0 + (long long)R * 1536 + C) = o;
                } else if constexpr (EPI == 2) {
                    long long idx = ((long long)(bz * 512 + R)) * 1536 + C;
                    u16x4 uu = *(const u16x4*)((const unsigned short*)p1 + idx);
                    u16x4 o;
#pragma unroll
                    for (int i = 0; i < 4; ++i) o[i] = f2b(a[i] * b2f(uu[i]));
                    *(u16x4*)((unsigned short*)p0 + idx) = o;
                } else {  // EPI == 3
                    long long idx = (long long)R * 768 + C;
                    f32x4 xv = *(const f32x4*)((const float*)p2 + idx);
                    f32x4 ob = *(const f32x4*)((const float*)p1 + C);
                    f32x4 o;
#pragma unroll
                    for (int i = 0; i < 4; ++i) o[i] = a[i] + ob[i] + xv[i];
                    *(f32x4*)((float*)p0 + idx) = o;
                }
            }
        }
    } else {  // EPI == 4 : vT
        int rowb = by * 256 + wr * 128 + (qq << 2);
        int colb = bx * 256 + wc * 64 + c15;
#pragma unroll
        for (int m = 0; m < 8; ++m) {
#pragma unroll
            for (int n = 0; n < 4; ++n) {
                int grow = rowb + m * 16;
                int e = colb + n * 16;
                float bias = ((const float*)p3)[1536 + e];
                f32x4 a = acc[m][n];
                u16x4 o;
#pragma unroll
                for (int i = 0; i < 4; ++i) o[i] = f2b(silu(a[i] + bias));
                int bb2 = grow >> 9, mm = grow & 511;
                *(u16x4*)((unsigned short*)p0 + ((long long)bb2 * 1536 + e) * 512 + mm) = o;
            }
        }
    }
}

extern "C" void kernel_launch(void* const* d_in, const int* in_sizes, int n_in,
                              void* d_out, int out_size, void* d_ws, size_t ws_size,
                              hipStream_t stream) {
    const float* x     = (const float*)d_in[0];
    const float* ln_g  = (const float*)d_in[1];
    const float* ln_b  = (const float*)d_in[2];
    const float* uv_W  = (const float*)d_in[3];
    const float* uv_b  = (const float*)d_in[4];
    const float* g_qk  = (const float*)d_in[5];
    const float* b_qk  = (const float*)d_in[6];
    const float* w_rel = (const float*)d_in[7];
    const float* o_W   = (const float*)d_in[8];
    const float* o_b   = (const float*)d_in[9];
    float* out = (float*)d_out;

    char* ws = (char*)d_ws;
    size_t off = 0;
    auto alloc = [&](size_t bytes) {
        void* p = ws + off;
        off += (bytes + 255) & ~(size_t)255;
        return p;
    };
    unsigned short* uvWT = (unsigned short*)alloc(3200ll * 768 * 2);
    unsigned short* oWT  = (unsigned short*)alloc(768ll * 1536 * 2);
    unsigned short* xn   = (unsigned short*)alloc(16384ll * 768 * 2);
    unsigned short* u    = (unsigned short*)alloc(16384ll * 1536 * 2);
    unsigned short* vT   = (unsigned short*)alloc(32ll * 1536 * 512 * 2);
    unsigned short* bS   = (unsigned short*)alloc(16384ll * 128 * 2);
    unsigned short* q    = (unsigned short*)alloc(32ll * 512 * 128 * 2);
    unsigned short* k    = (unsigned short*)alloc(32ll * 512 * 128 * 2);
    unsigned short* P     = xn;  // alias: xn dead after GEMM1 trio
    unsigned short* gated = u;   // alias: same-thread read-then-write

    k_convT<<<dim3(100, 24), dim3(32, 8), 0, stream>>>(uv_W, uvWT, 768, 3200);
    k_convT<<<dim3(24, 48), dim3(32, 8), 0, stream>>>(o_W, oWT, 1536, 768);
    k_ln<<<16384, 256, 0, stream>>>(x, ln_g, ln_b, xn);
    // GEMM1: u | vT | bS
    k_gemm8<0, true, true><<<dim3(6, 64), 512, 0, stream>>>(
        xn, uvWT, 768, 0, 0, (void*)u, nullptr, nullptr, (const void*)uv_b);
    k_gemm8<4, false, true><<<dim3(6, 64), 512, 0, stream>>>(
        xn, uvWT + 1536ll * 768, 768, 0, 0, (void*)vT, nullptr, nullptr, (const void*)uv_b);
    k_gemm<5, true, true><<<dim3(1, 128), 256, 0, stream>>>(
        xn, uvWT + 3072ll * 768, 768, 0, 0, (void*)bS, nullptr, nullptr,
        (const void*)(uv_b + 3072));
    k_rope<<<16384, 128, 0, stream>>>(bS, g_qk, b_qk, q, k);
    // QK^T -> P
    k_gemm<1, true, false><<<dim3(4, 4, 32), 256, 0, stream>>>(
        q, k, 128, 512ll * 128, 512ll * 128, (void*)P, (const void*)w_rel, nullptr, nullptr);
    // PV gated by u
    k_gemm8<2, true, false><<<dim3(6, 2, 32), 512, 0, stream>>>(
        P, vT, 512, 512ll * 512, 1536ll * 512, (void*)gated, (const void*)u, nullptr, nullptr);
    // out = gated @ oWT^T + o_b + x
    k_gemm8<3, true, true><<<dim3(3, 64), 512, 0, stream>>>(
        gated, oWT, 1536, 0, 0, (void*)out, (const void*)o_b, (const void*)x, nullptr);
}